// Round 3
// baseline (502.614 us; speedup 1.0000x reference)
//
#include <hip/hip_runtime.h>
#include <math.h>

#define NHID 128

typedef __bf16 bf16x8 __attribute__((ext_vector_type(8)));
typedef float f32x4 __attribute__((ext_vector_type(4)));

// pack two fp32 -> two bf16 (round-to-nearest): 3 VALU ops
__device__ __forceinline__ unsigned int pack_bf16_rn(float f0, float f1) {
  unsigned int u0 = __float_as_uint(f0) + 0x8000u;
  unsigned int u1 = __float_as_uint(f1) + 0x8000u;
  return __builtin_amdgcn_perm(u1, u0, 0x07060302u);   // hi16(u1):hi16(u0)
}

union frag_u { unsigned int u[4]; bf16x8 v; };

__global__ __launch_bounds__(512, 4)   // cap 128 regs; budget ~110 -> no spill
void mlp_edge_decoder(const float* __restrict__ inputs,
                      const int* __restrict__ x_idx,
                      const int* __restrict__ y_idx,
                      const float* __restrict__ W1,
                      const float* __restrict__ bias1,
                      const float* __restrict__ W2,
                      const float* __restrict__ bias2,
                      float* __restrict__ out,
                      int n_edges)
{
  // W1 in MFMA B-fragment-major order (verified round 1/2 numerics):
  // sB[((ks*8+nt)*64+lane)*8+j] = bf16(W1[k=ks*32+(lane>>4)*8+j][n=nt*16+(lane&15)])
  // 64 KB exactly -> 2 blocks/CU, 16 waves/CU at 512 threads.
  __shared__ __align__(16) unsigned short sB[8 * 8 * 64 * 8];

  const int tid = threadIdx.x;
  for (int i = tid; i < 256 * NHID / 4; i += 512) {
    float4 w = ((const float4*)W1)[i];
    int base = i * 4;
    int k  = base >> 7;          // W1 row-major [k][n]
    int n0 = base & 127;
    int ks = k >> 5, qq = (k >> 3) & 3, j = k & 7;
    #pragma unroll
    for (int c = 0; c < 4; ++c) {
      int n = n0 + c;
      int nt = n >> 4, m = n & 15;
      int ln = qq * 16 + m;
      unsigned int u = __float_as_uint((&w.x)[c]) + 0x8000u;
      sB[(((ks * 8 + nt) * 64) + ln) * 8 + j] = (unsigned short)(u >> 16);
    }
  }
  __syncthreads();   // only barrier; all waves independent afterwards

  const int lane = tid & 63;
  const int wv   = tid >> 6;
  const int m15  = lane & 15;
  const int q    = lane >> 4;

  // per-lane epilogue constants: col n = nt*16 + m15
  float b1v[8], w2v[8];
  #pragma unroll
  for (int nt = 0; nt < 8; ++nt) {
    b1v[nt] = bias1[nt * 16 + m15];
    w2v[nt] = W2[nt * 16 + m15];
  }
  const float b2 = bias2[0];

  const int gwave   = blockIdx.x * 8 + wv;
  const int nwaves  = gridDim.x * 8;
  const int nstrips = (n_edges + 15) >> 4;   // 16-edge strips (500000/16 = 31250 exact)

  const bf16x8* __restrict__ bfrags = (const bf16x8*)sB;

  // pipeline the index loads one strip ahead (removes serial idx->gather dependency)
  int ix_n = 0, iy_n = 0;
  if (gwave < nstrips) {
    int e = gwave * 16 + m15;
    if (e >= n_edges) e = n_edges - 1;
    ix_n = x_idx[e];
    iy_n = y_idx[e];
  }

  for (int strip = gwave; strip < nstrips; strip += nwaves) {
    const float* ax = inputs + (size_t)ix_n * NHID;   // this lane's edge row (row = m15)
    const float* ay = inputs + (size_t)iy_n * NHID;

    // prefetch next strip's node indices now
    int nxt = strip + nwaves;
    if (nxt < nstrips) {
      int e = nxt * 16 + m15;
      if (e >= n_edges) e = n_edges - 1;
      ix_n = x_idx[e];
      iy_n = y_idx[e];
    }

    // depth-4 ring of raw fp32 A fragments: 8 loads in flight (32 regs)
    // per ks, lane covers bytes [ks*128 + q*32, +32) of its row -> full sectors used
    float4 ring0[4], ring1[4];
    #pragma unroll
    for (int d = 0; d < 4; ++d) {
      ring0[d] = *(const float4*)(ax + d * 32 + q * 8);
      ring1[d] = *(const float4*)(ax + d * 32 + q * 8 + 4);
    }

    f32x4 acc[8];
    #pragma unroll
    for (int nt = 0; nt < 8; ++nt)
      acc[nt] = (f32x4){0.f, 0.f, 0.f, 0.f};

    #pragma unroll
    for (int ks = 0; ks < 8; ++ks) {
      float4 a0 = ring0[ks & 3], a1 = ring1[ks & 3];
      frag_u cv;
      cv.u[0] = pack_bf16_rn(a0.x, a0.y);
      cv.u[1] = pack_bf16_rn(a0.z, a0.w);
      cv.u[2] = pack_bf16_rn(a1.x, a1.y);
      cv.u[3] = pack_bf16_rn(a1.z, a1.w);
      bf16x8 af = cv.v;
      if (ks < 4) {   // refill ring slot with the y-node half (k = 128..255)
        ring0[ks & 3] = *(const float4*)(ay + ks * 32 + q * 8);
        ring1[ks & 3] = *(const float4*)(ay + ks * 32 + q * 8 + 4);
      }
      const bf16x8* bp = bfrags + (ks * 8) * 64 + lane;
      #pragma unroll
      for (int nt = 0; nt < 8; ++nt)
        acc[nt] = __builtin_amdgcn_mfma_f32_16x16x32_bf16(af, bp[nt * 64], acc[nt], 0, 0, 0);
    }

    // ---- epilogue in-register: bias+relu+W2 dot, 16-lane reduce, store ----
    // D layout: col = lane&15 (n within tile), row = q*4 + r (edge within strip)
    float4 sv;
    #pragma unroll
    for (int r = 0; r < 4; ++r) {
      float t = 0.f;
      #pragma unroll
      for (int nt = 0; nt < 8; ++nt) {
        float h = acc[nt][r] + b1v[nt];
        h = fmaxf(h, 0.f);
        t = fmaf(h, w2v[nt], t);
      }
      t += __shfl_xor(t, 1);
      t += __shfl_xor(t, 2);
      t += __shfl_xor(t, 4);
      t += __shfl_xor(t, 8);
      (&sv.x)[r] = t;
    }
    if (m15 == 0) {
      int e = strip * 16 + q * 4;   // lanes 0,16,32,48 -> contiguous 64B
      float4 ov;
      #pragma unroll
      for (int r = 0; r < 4; ++r)
        (&ov.x)[r] = 1.f / (1.f + __expf(-((&sv.x)[r] + b2)));
      if (e + 3 < n_edges) {
        *(float4*)(out + e) = ov;
      } else {
        #pragma unroll
        for (int r = 0; r < 4; ++r)
          if (e + r < n_edges) out[e + r] = (&ov.x)[r];
      }
    }
  }
}

extern "C" void kernel_launch(void* const* d_in, const int* in_sizes, int n_in,
                              void* d_out, int out_size, void* d_ws, size_t ws_size,
                              hipStream_t stream) {
  const float* inputs = (const float*)d_in[0];
  const int*   x_idx  = (const int*)d_in[1];
  const int*   y_idx  = (const int*)d_in[2];
  const float* W1     = (const float*)d_in[3];
  const float* bias1  = (const float*)d_in[4];
  const float* W2     = (const float*)d_in[5];
  const float* bias2  = (const float*)d_in[6];
  float* out = (float*)d_out;
  const int n_edges = in_sizes[1];

  // 512 blocks x 512 threads: 2 blocks/CU (64 KB LDS), 16 waves/CU
  hipLaunchKernelGGL(mlp_edge_decoder, dim3(512), dim3(512), 0, stream,
                     inputs, x_idx, y_idx, W1, bias1, W2, bias2, out, n_edges);
}

// Round 4
// 220.506 us; speedup vs baseline: 2.2794x; 2.2794x over previous
//
#include <hip/hip_runtime.h>
#include <math.h>

#define NHID 128

typedef __bf16 bf16x8 __attribute__((ext_vector_type(8)));
typedef float f32x4 __attribute__((ext_vector_type(4)));

__device__ __forceinline__ unsigned int pack_bf16_rn(float f0, float f1) {
  unsigned int u0 = __float_as_uint(f0) + 0x8000u;
  unsigned int u1 = __float_as_uint(f1) + 0x8000u;
  return __builtin_amdgcn_perm(u1, u0, 0x07060302u);   // hi16(u1):hi16(u0)
}
__device__ __forceinline__ unsigned short f2bf(float f) {
  return (unsigned short)((__float_as_uint(f) + 0x8000u) >> 16);
}
union frag_u { unsigned int u[4]; bf16x8 v; };

// ============================================================================
// Phase 1: C[node][0:128] = node@W1a + b1 (bf16), C[node][128:256] = node@W1b
// Dense GEMM M=n_nodes, N=256, K=128. Sequential A reads, no gather.
// ============================================================================
__global__ __launch_bounds__(256, 2)   // 256-reg cap: no spill (lesson of r2/r3)
void precompute_uv(const float* __restrict__ inputs,
                   const float* __restrict__ W1,
                   const float* __restrict__ bias1,
                   unsigned short* __restrict__ C,
                   int n_nodes)
{
  // Combined B (K=128, N=256): Bc[k][n] = n<128 ? W1[k][n] : W1[128+k][n-128]
  // staged in MFMA B-frag-major order (layout verified rounds 1-3): 64 KB
  __shared__ __align__(16) unsigned short sB[4 * 16 * 64 * 8];

  const int tid = threadIdx.x;
  for (int i = tid; i < 256 * NHID / 4; i += 256) {
    float4 w = ((const float4*)W1)[i];
    int base = i * 4;
    int r  = base >> 7;          // W1 row (0..255)
    int n0 = base & 127;
    int k  = (r < 128) ? r : (r - 128);
    int nb = (r < 128) ? n0 : (n0 + 128);
    int ks = k >> 5, q = (k >> 3) & 3, j = k & 7;
    #pragma unroll
    for (int c = 0; c < 4; ++c) {
      int n = nb + c;
      int nt = n >> 4, m = n & 15;
      sB[(((ks * 16 + nt) * 64) + (q * 16 + m)) * 8 + j] = f2bf((&w.x)[c]);
    }
  }
  __syncthreads();

  const int lane = tid & 63;
  const int wv   = tid >> 6;
  const int m15  = lane & 15;
  const int q    = lane >> 4;

  float b1v[8];
  #pragma unroll
  for (int nt = 0; nt < 8; ++nt) b1v[nt] = bias1[nt * 16 + m15];

  const bf16x8* __restrict__ bfrags = (const bf16x8*)sB;
  const int gwave   = blockIdx.x * 4 + wv;
  const int nwaves  = gridDim.x * 4;
  const int nstrips = (n_nodes + 15) >> 4;

  for (int strip = gwave; strip < nstrips; strip += nwaves) {
    int row = strip * 16 + m15;
    if (row >= n_nodes) row = n_nodes - 1;
    const float* ap = inputs + (size_t)row * NHID;

    // A-frag (verified): row = m15, k = ks*32 + q*8 + j
    float4 r0[4], r1[4];
    #pragma unroll
    for (int ks = 0; ks < 4; ++ks) {
      r0[ks] = *(const float4*)(ap + ks * 32 + q * 8);
      r1[ks] = *(const float4*)(ap + ks * 32 + q * 8 + 4);
    }

    f32x4 acc[16];
    #pragma unroll
    for (int nt = 0; nt < 16; ++nt) acc[nt] = (f32x4){0.f, 0.f, 0.f, 0.f};

    #pragma unroll
    for (int ks = 0; ks < 4; ++ks) {
      frag_u cv;
      cv.u[0] = pack_bf16_rn(r0[ks].x, r0[ks].y);
      cv.u[1] = pack_bf16_rn(r0[ks].z, r0[ks].w);
      cv.u[2] = pack_bf16_rn(r1[ks].x, r1[ks].y);
      cv.u[3] = pack_bf16_rn(r1[ks].z, r1[ks].w);
      bf16x8 af = cv.v;
      const bf16x8* bp = bfrags + (ks * 16) * 64 + lane;
      #pragma unroll
      for (int nt = 0; nt < 16; ++nt)
        acc[nt] = __builtin_amdgcn_mfma_f32_16x16x32_bf16(af, bp[nt * 64], acc[nt], 0, 0, 0);
    }

    // D layout (verified): col = lane&15, row = q*4 + r. Fold b1 into u half.
    #pragma unroll
    for (int r = 0; r < 4; ++r) {
      int m = strip * 16 + q * 4 + r;
      bool ok = (m < n_nodes) && ((m15 & 1) == 0);
      unsigned short* crow = C + (size_t)m * 256;
      #pragma unroll
      for (int nt = 0; nt < 16; ++nt) {
        float val = acc[nt][r] + ((nt < 8) ? b1v[nt] : 0.f);
        float oth = __shfl_xor(val, 1);          // neighbor col (m15^1)
        if (ok) {
          unsigned int pk = pack_bf16_rn(val, oth);
          *(unsigned int*)(crow + nt * 16 + m15) = pk;
        }
      }
    }
  }
}

// ============================================================================
// Phase 2: out[e] = sigmoid( sum_j relu(u[x_idx[e]][j] + v[y_idx[e]][j]) * W2[j] + b2 )
// Pure gather + elementwise. 16 lanes per edge; 4 edges per wave per iter.
// ============================================================================
__global__ __launch_bounds__(256, 4)
void edge_decode(const unsigned short* __restrict__ C,
                 const int* __restrict__ x_idx,
                 const int* __restrict__ y_idx,
                 const float* __restrict__ W2,
                 const float* __restrict__ bias2,
                 float* __restrict__ out,
                 int n_edges)
{
  const int tid  = threadIdx.x;
  const int lane = tid & 63;
  const int wv   = tid >> 6;
  const int sub  = lane & 15;   // 16-B slice of the 256-B row
  const int eo   = lane >> 4;   // edge within wave batch

  float w2v[8];
  #pragma unroll
  for (int j = 0; j < 8; ++j) w2v[j] = W2[sub * 8 + j];
  const float b2 = bias2[0];

  const int gwave = blockIdx.x * 4 + wv;
  const int se    = gridDim.x * 4 * 4;       // edges per grid step
  int e = gwave * 4;
  if (e >= n_edges) return;

  // prologue: indices + rows for iter 0, indices for iter 1
  int ec = e + eo; if (ec >= n_edges) ec = n_edges - 1;
  int xi = x_idx[ec], yi = y_idx[ec];
  uint4 Ru = *(const uint4*)(C + (size_t)xi * 256 + sub * 8);
  uint4 Rv = *(const uint4*)(C + (size_t)yi * 256 + 128 + sub * 8);
  int xin = 0, yin = 0;
  {
    int en = e + se;
    if (en < n_edges) {
      int ecn = en + eo; if (ecn >= n_edges) ecn = n_edges - 1;
      xin = x_idx[ecn]; yin = y_idx[ecn];
    }
  }

  for (; e < n_edges; e += se) {
    const int en = e + se;
    uint4 Run, Rvn;
    if (en < n_edges) {   // issue next rows now; latency hides under compute
      Run = *(const uint4*)(C + (size_t)xin * 256 + sub * 8);
      Rvn = *(const uint4*)(C + (size_t)yin * 256 + 128 + sub * 8);
      int en2 = en + se;
      if (en2 < n_edges) {
        int ec2 = en2 + eo; if (ec2 >= n_edges) ec2 = n_edges - 1;
        xin = x_idx[ec2]; yin = y_idx[ec2];
      }
    }

    float t = 0.f;
    #pragma unroll
    for (int p = 0; p < 4; ++p) {
      unsigned int a = (&Ru.x)[p], b = (&Rv.x)[p];
      float alo = __uint_as_float(a << 16);
      float ahi = __uint_as_float(a & 0xffff0000u);
      float blo = __uint_as_float(b << 16);
      float bhi = __uint_as_float(b & 0xffff0000u);
      float h0 = fmaxf(alo + blo, 0.f);          // b1 already folded into u
      float h1 = fmaxf(ahi + bhi, 0.f);
      t = fmaf(h0, w2v[2 * p], t);
      t = fmaf(h1, w2v[2 * p + 1], t);
    }
    t += __shfl_xor(t, 1);
    t += __shfl_xor(t, 2);
    t += __shfl_xor(t, 4);
    t += __shfl_xor(t, 8);
    int epos = e + eo;
    if (sub == 0 && epos < n_edges)
      out[epos] = 1.f / (1.f + __expf(-(t + b2)));

    Ru = Run; Rv = Rvn;
  }
}

// ============================================================================
// Fallback (ws too small): fused kernel, round-3 structure at 256 threads with
// a 256-reg cap (the no-spill configuration proven in round 1).
// ============================================================================
__global__ __launch_bounds__(256, 2)
void mlp_edge_fused(const float* __restrict__ inputs,
                    const int* __restrict__ x_idx,
                    const int* __restrict__ y_idx,
                    const float* __restrict__ W1,
                    const float* __restrict__ bias1,
                    const float* __restrict__ W2,
                    const float* __restrict__ bias2,
                    float* __restrict__ out,
                    int n_edges)
{
  __shared__ __align__(16) unsigned short sB[8 * 8 * 64 * 8];
  const int tid = threadIdx.x;
  for (int i = tid; i < 256 * NHID / 4; i += 256) {
    float4 w = ((const float4*)W1)[i];
    int base = i * 4;
    int k  = base >> 7;
    int n0 = base & 127;
    int ks = k >> 5, qq = (k >> 3) & 3, j = k & 7;
    #pragma unroll
    for (int c = 0; c < 4; ++c) {
      int n = n0 + c;
      sB[(((ks * 8 + (n >> 4)) * 64) + (qq * 16 + (n & 15))) * 8 + j] = f2bf((&w.x)[c]);
    }
  }
  __syncthreads();

  const int lane = tid & 63;
  const int wv   = tid >> 6;
  const int m15  = lane & 15;
  const int q    = lane >> 4;

  float b1v[8], w2v[8];
  #pragma unroll
  for (int nt = 0; nt < 8; ++nt) {
    b1v[nt] = bias1[nt * 16 + m15];
    w2v[nt] = W2[nt * 16 + m15];
  }
  const float b2 = bias2[0];

  const int gwave   = blockIdx.x * 4 + wv;
  const int nwaves  = gridDim.x * 4;
  const int nstrips = (n_edges + 15) >> 4;
  const bf16x8* __restrict__ bfrags = (const bf16x8*)sB;

  int ix_n = 0, iy_n = 0;
  if (gwave < nstrips) {
    int e = gwave * 16 + m15; if (e >= n_edges) e = n_edges - 1;
    ix_n = x_idx[e]; iy_n = y_idx[e];
  }

  for (int strip = gwave; strip < nstrips; strip += nwaves) {
    const float* ax = inputs + (size_t)ix_n * NHID;
    const float* ay = inputs + (size_t)iy_n * NHID;
    int nxt = strip + nwaves;
    if (nxt < nstrips) {
      int e = nxt * 16 + m15; if (e >= n_edges) e = n_edges - 1;
      ix_n = x_idx[e]; iy_n = y_idx[e];
    }
    float4 ring0[4], ring1[4];
    #pragma unroll
    for (int d = 0; d < 4; ++d) {
      ring0[d] = *(const float4*)(ax + d * 32 + q * 8);
      ring1[d] = *(const float4*)(ax + d * 32 + q * 8 + 4);
    }
    f32x4 acc[8];
    #pragma unroll
    for (int nt = 0; nt < 8; ++nt) acc[nt] = (f32x4){0.f, 0.f, 0.f, 0.f};
    #pragma unroll
    for (int ks = 0; ks < 8; ++ks) {
      float4 a0 = ring0[ks & 3], a1 = ring1[ks & 3];
      frag_u cv;
      cv.u[0] = pack_bf16_rn(a0.x, a0.y);
      cv.u[1] = pack_bf16_rn(a0.z, a0.w);
      cv.u[2] = pack_bf16_rn(a1.x, a1.y);
      cv.u[3] = pack_bf16_rn(a1.z, a1.w);
      bf16x8 af = cv.v;
      if (ks < 4) {
        ring0[ks & 3] = *(const float4*)(ay + ks * 32 + q * 8);
        ring1[ks & 3] = *(const float4*)(ay + ks * 32 + q * 8 + 4);
      }
      const bf16x8* bp = bfrags + (ks * 8) * 64 + lane;
      #pragma unroll
      for (int nt = 0; nt < 8; ++nt)
        acc[nt] = __builtin_amdgcn_mfma_f32_16x16x32_bf16(af, bp[nt * 64], acc[nt], 0, 0, 0);
    }
    float4 sv;
    #pragma unroll
    for (int r = 0; r < 4; ++r) {
      float t = 0.f;
      #pragma unroll
      for (int nt = 0; nt < 8; ++nt) {
        float h = acc[nt][r] + b1v[nt];
        h = fmaxf(h, 0.f);
        t = fmaf(h, w2v[nt], t);
      }
      t += __shfl_xor(t, 1);
      t += __shfl_xor(t, 2);
      t += __shfl_xor(t, 4);
      t += __shfl_xor(t, 8);
      (&sv.x)[r] = t;
    }
    if (m15 == 0) {
      int e = strip * 16 + q * 4;
      float4 ov;
      #pragma unroll
      for (int r = 0; r < 4; ++r)
        (&ov.x)[r] = 1.f / (1.f + __expf(-((&sv.x)[r] + b2)));
      if (e + 3 < n_edges) *(float4*)(out + e) = ov;
      else {
        #pragma unroll
        for (int r = 0; r < 4; ++r)
          if (e + r < n_edges) out[e + r] = (&ov.x)[r];
      }
    }
  }
}

extern "C" void kernel_launch(void* const* d_in, const int* in_sizes, int n_in,
                              void* d_out, int out_size, void* d_ws, size_t ws_size,
                              hipStream_t stream) {
  const float* inputs = (const float*)d_in[0];
  const int*   x_idx  = (const int*)d_in[1];
  const int*   y_idx  = (const int*)d_in[2];
  const float* W1     = (const float*)d_in[3];
  const float* bias1  = (const float*)d_in[4];
  const float* W2     = (const float*)d_in[5];
  const float* bias2  = (const float*)d_in[6];
  float* out = (float*)d_out;
  const int n_edges = in_sizes[1];
  const int n_nodes = in_sizes[0] / NHID;

  const size_t need = (size_t)n_nodes * 256 * sizeof(unsigned short);
  if (ws_size >= need) {
    unsigned short* C = (unsigned short*)d_ws;
    hipLaunchKernelGGL(precompute_uv, dim3(512), dim3(256), 0, stream,
                       inputs, W1, bias1, C, n_nodes);
    hipLaunchKernelGGL(edge_decode, dim3(2048), dim3(256), 0, stream,
                       C, x_idx, y_idx, W2, bias2, out, n_edges);
  } else {
    hipLaunchKernelGGL(mlp_edge_fused, dim3(512), dim3(256), 0, stream,
                       inputs, x_idx, y_idx, W1, bias1, W2, bias2, out, n_edges);
  }
}